// Round 1
// baseline (629.444 us; speedup 1.0000x reference)
//
#include <hip/hip_runtime.h>

#define DI __device__ __forceinline__

typedef float f32x4 __attribute__((ext_vector_type(4)));
typedef short s16x8 __attribute__((ext_vector_type(8)));

constexpr int N_ = 64, T_ = 300, V_ = 25, C_ = 64, K_ = 3, F_ = 64, I_ = 16;

// round-to-nearest-even f32 -> bf16 (as raw short)
DI short f2bf(float f) {
  union { float f; unsigned u; } v; v.f = f;
  unsigned r = (v.u + 0x7fffu + ((v.u >> 16) & 1u)) >> 16;
  return (short)r;
}

// ---------------------------------------------------------------------------
// K1: per (n, chunk of 4 t's): P = x @ [Wq|Wk] + [bq|bk]  (rows=(t,v), cols=96)
//     then S_k[v][w] += sum_{t,i} q[t,v,i]*k[t,w,i]  (atomicAdd partials to ws)
// ---------------------------------------------------------------------------
__global__ __launch_bounds__(256, 2) void k1_scores(
    const float* __restrict__ x,
    const float* __restrict__ Wq, const float* __restrict__ bq,
    const float* __restrict__ Wk, const float* __restrict__ bk,
    float* __restrict__ Sacc)
{
  __shared__ __align__(16) short Xl[112 * 64];   // rows=(t,v) pad->112, cols=c (swz)
  __shared__ __align__(16) short Wt[96 * 64];    // rows=j(96), cols=c (swz)
  __shared__ __align__(16) short Pq[4 * 32 * 64];// [t][v(32)][j<48 pad 64] (swz by v)
  __shared__ __align__(16) short Pk[4 * 32 * 64];
  __shared__ float bcl[96];

  const int tid = threadIdx.x;
  const int lane = tid & 63;
  const int wid = tid >> 6;
  const int g = lane >> 4;
  const int lo = lane & 15;
  const int n = blockIdx.y;
  const int t0row = blockIdx.x * 100;  // 4 t's * 25 v

  // stage combined q/k weights, transposed+swizzled: Wt[j][c] = Wc[c][j]
  for (int idx = tid; idx < 96 * 64; idx += 256) {
    int j = idx >> 6, c = idx & 63;
    float v;
    if (j < 48) v = Wq[(j >> 4) * (C_ * I_) + c * I_ + (j & 15)];
    else { int j2 = j - 48; v = Wk[(j2 >> 4) * (C_ * I_) + c * I_ + (j2 & 15)]; }
    Wt[j * 64 + (c ^ ((j & 7) << 3))] = f2bf(v);
  }
  if (tid < 96) bcl[tid] = (tid < 48) ? bq[tid] : bk[tid - 48];

  // stage x chunk (100 valid rows, pad rows zeroed)
  {
    const float* xb = x + (size_t)n * (T_ * V_ * C_) + (size_t)t0row * C_;
    for (int idx = tid; idx < 112 * 64; idx += 256) {
      int row = idx >> 6, c = idx & 63;
      float v = (row < 100) ? xb[idx] : 0.f;
      Xl[row * 64 + (c ^ ((row & 7) << 3))] = f2bf(v);
    }
  }
  __syncthreads();

  // P-stage: 7 m-tiles x 6 n-tiles, K=64 (2 steps of 32)
  for (int i = 0; i < 11; ++i) {
    int tile = wid + i * 4;
    if (tile >= 42) break;
    int m = tile / 6, nt = tile % 6;
    float binit = bcl[nt * 16 + lo];
    f32x4 acc = { binit, binit, binit, binit };
#pragma unroll
    for (int ks = 0; ks < 2; ++ks) {
      int arow = m * 16 + lo;
      s16x8 a = *(const s16x8*)&Xl[arow * 64 + ((ks * 32 + g * 8) ^ ((arow & 7) << 3))];
      int brow = nt * 16 + lo;
      s16x8 b = *(const s16x8*)&Wt[brow * 64 + ((ks * 32 + g * 8) ^ ((brow & 7) << 3))];
      acc = __builtin_amdgcn_mfma_f32_16x16x32_bf16(a, b, acc, 0, 0, 0);
    }
#pragma unroll
    for (int r = 0; r < 4; ++r) {
      int row = m * 16 + g * 4 + r;
      if (row < 100) {
        int t = row / 25, v = row - t * 25;
        int j = nt * 16 + lo;
        short val = f2bf(acc[r]);
        if (j < 48) Pq[(t * 32 + v) * 64 + (j ^ ((v & 7) << 3))] = val;
        else        Pk[(t * 32 + v) * 64 + ((j - 48) ^ ((v & 7) << 3))] = val;
      }
    }
  }
  __syncthreads();

  // S-stage: combos (k, vt, wt), K-dim = (t,i) = 64 -> 2 steps of 32
#pragma unroll
  for (int i = 0; i < 3; ++i) {
    int combo = wid + i * 4;          // 0..11
    int k = combo >> 2, vt = (combo >> 1) & 1, wt = combo & 1;
    f32x4 acc = { 0.f, 0.f, 0.f, 0.f };
#pragma unroll
    for (int ks = 0; ks < 2; ++ks) {
      int t = ks * 2 + (g >> 1);
      int ib = (g & 1) * 8;
      int v = vt * 16 + lo;
      s16x8 a = *(const s16x8*)&Pq[(t * 32 + v) * 64 + ((k * 16 + ib) ^ ((v & 7) << 3))];
      int w = wt * 16 + lo;
      s16x8 b = *(const s16x8*)&Pk[(t * 32 + w) * 64 + ((k * 16 + ib) ^ ((w & 7) << 3))];
      acc = __builtin_amdgcn_mfma_f32_16x16x32_bf16(a, b, acc, 0, 0, 0);
    }
#pragma unroll
    for (int r = 0; r < 4; ++r) {
      int v = vt * 16 + g * 4 + r;
      int w = wt * 16 + lo;
      if (v < 25 && w < 25)
        atomicAdd(&Sacc[((size_t)(k * 64 + n) * 25 + v) * 25 + w], acc[r]);
    }
  }
}

// ---------------------------------------------------------------------------
// K2: softmax(S*scale) + A -> AadT (transposed [w][v], bf16, zero-padded 32x32)
// ---------------------------------------------------------------------------
__global__ void k2_softmax(const float* __restrict__ Sacc,
                           const float* __restrict__ A,
                           unsigned short* __restrict__ AadT)
{
  int bx = blockIdx.x;            // 0..191 = k*64 + n
  int k = bx >> 6;
  int tid = threadIdx.x;          // 64
  unsigned short* outb = AadT + (size_t)bx * 1024;
  for (int idx = tid; idx < 1024; idx += 64) outb[idx] = 0;
  __syncthreads();
  if (tid < 25) {
    int v = tid;
    const float* srow = Sacc + ((size_t)bx * 25 + v) * 25;
    const float scale = 0.014433756729740645f;  // 1/sqrt(4800)
    float s[25];
    float mx = -1e30f;
#pragma unroll
    for (int w = 0; w < 25; ++w) { s[w] = srow[w] * scale; mx = fmaxf(mx, s[w]); }
    float sum = 0.f;
#pragma unroll
    for (int w = 0; w < 25; ++w) { s[w] = __expf(s[w] - mx); sum += s[w]; }
    float inv = 1.f / sum;
#pragma unroll
    for (int w = 0; w < 25; ++w) {
      float aad = A[(k * 25 + v) * 25 + w] + s[w] * inv;
      outb[w * 32 + v] = (unsigned short)f2bf(aad);
    }
  }
}

// ---------------------------------------------------------------------------
// K3: per (n, chunk of 3 t's): h = x@W + b (MFMA, store transposed in LDS),
//     y[t][w][c] = sum_k sum_v AadT[k][w][v] * h[t][v][k*64+c] (MFMA), store y.
// ---------------------------------------------------------------------------
__global__ __launch_bounds__(256, 2) void k3_main(
    const float* __restrict__ x,
    const float* __restrict__ W, const float* __restrict__ b,
    const unsigned short* __restrict__ AadT, float* __restrict__ y)
{
  __shared__ __align__(16) short Xl[80 * 64];    // rows=(t,v) pad->80, cols=c (swz)
  __shared__ __align__(16) short Wt[192 * 64];   // rows=kc, cols=c (swz)
  __shared__ __align__(16) short Ht[192 * 96];   // rows=kc, cols=(t*32+v) (swz &3)
  __shared__ __align__(16) short Al[3 * 32 * 32];// [k][w][v] (swz &3)
  __shared__ float bl[192];

  const int tid = threadIdx.x;
  const int lane = tid & 63;
  const int wid = tid >> 6;
  const int g = lane >> 4;
  const int lo = lane & 15;
  const int n = blockIdx.y;
  const int t0 = blockIdx.x * 3;

  // stage W transposed+swizzled (coalesced global reads)
  for (int idx = tid; idx < 192 * 64; idx += 256) {
    int c = idx / 192, j = idx % 192;
    Wt[j * 64 + (c ^ ((j & 7) << 3))] = f2bf(W[idx]);
  }
  if (tid < 192) bl[tid] = b[tid];

  // stage AadT into LDS (swizzled); ws already zero-padded
  for (int idx = tid; idx < 3 * 1024; idx += 256) {
    int kk = idx >> 10, rem = idx & 1023, w = rem >> 5, v = rem & 31;
    unsigned short val = AadT[(size_t)(kk * 64 + n) * 1024 + rem];
    Al[(kk * 32 + w) * 32 + (v ^ ((w & 3) << 3))] = (short)val;
  }

  // zero Ht pad slots (v = 24..31) so 0*pad is clean in agg MFMA
  for (int idx = tid; idx < 192 * 24; idx += 256) {
    int kc = idx / 24, rem = idx % 24, t = rem >> 3, vv = 24 + (rem & 7);
    Ht[kc * 96 + ((t * 32 + vv) ^ ((kc & 3) << 3))] = 0;
  }

  // stage x chunk (75 valid rows)
  {
    const float* xb = x + (size_t)n * (T_ * V_ * C_) + (size_t)t0 * (V_ * C_);
    for (int idx = tid; idx < 80 * 64; idx += 256) {
      int row = idx >> 6, c = idx & 63;
      float v = (row < 75) ? xb[idx] : 0.f;
      Xl[row * 64 + (c ^ ((row & 7) << 3))] = f2bf(v);
    }
  }
  __syncthreads();

  // h-stage: 5 m-tiles x 12 n-tiles, K=64 (2 steps); store transposed into Ht
#pragma unroll
  for (int i = 0; i < 15; ++i) {
    int tile = wid + i * 4;            // 0..59
    int m = tile / 12, nt = tile % 12;
    float binit = bl[nt * 16 + lo];
    f32x4 acc = { binit, binit, binit, binit };
#pragma unroll
    for (int ks = 0; ks < 2; ++ks) {
      int arow = m * 16 + lo;
      s16x8 a = *(const s16x8*)&Xl[arow * 64 + ((ks * 32 + g * 8) ^ ((arow & 7) << 3))];
      int brow = nt * 16 + lo;
      s16x8 bb = *(const s16x8*)&Wt[brow * 64 + ((ks * 32 + g * 8) ^ ((brow & 7) << 3))];
      acc = __builtin_amdgcn_mfma_f32_16x16x32_bf16(a, bb, acc, 0, 0, 0);
    }
#pragma unroll
    for (int r = 0; r < 4; ++r) {
      int row = m * 16 + g * 4 + r;
      if (row < 75) {
        int t = row / 25, v = row - t * 25;
        int kc = nt * 16 + lo;
        Ht[kc * 96 + ((t * 32 + v) ^ ((kc & 3) << 3))] = f2bf(acc[r]);
      }
    }
  }
  __syncthreads();

  // agg: jobs (t, wt, ct); K-dim = v (32, one step); accumulate over k
#pragma unroll
  for (int i = 0; i < 6; ++i) {
    int job = wid + i * 4;             // 0..23
    int t = job >> 3, rem = job & 7, wt = rem >> 2, ct = rem & 3;
    f32x4 acc = { 0.f, 0.f, 0.f, 0.f };
#pragma unroll
    for (int k3 = 0; k3 < 3; ++k3) {
      int w = wt * 16 + lo;
      s16x8 a = *(const s16x8*)&Al[(k3 * 32 + w) * 32 + ((g * 8) ^ ((w & 3) << 3))];
      int kc = k3 * 64 + ct * 16 + lo;
      s16x8 bb = *(const s16x8*)&Ht[kc * 96 + ((t * 32 + g * 8) ^ ((kc & 3) << 3))];
      acc = __builtin_amdgcn_mfma_f32_16x16x32_bf16(a, bb, acc, 0, 0, 0);
    }
#pragma unroll
    for (int r = 0; r < 4; ++r) {
      int w = wt * 16 + g * 4 + r;
      if (w < 25)
        y[(((size_t)n * T_ + t0 + t) * V_ + w) * C_ + ct * 16 + lo] = acc[r];
    }
  }
}

extern "C" void kernel_launch(void* const* d_in, const int* in_sizes, int n_in,
                              void* d_out, int out_size, void* d_ws, size_t ws_size,
                              hipStream_t stream) {
  const float* x  = (const float*)d_in[0];
  const float* A  = (const float*)d_in[1];
  const float* W  = (const float*)d_in[2];
  const float* b  = (const float*)d_in[3];
  const float* Wq = (const float*)d_in[4];
  const float* bq = (const float*)d_in[5];
  const float* Wk = (const float*)d_in[6];
  const float* bk = (const float*)d_in[7];
  float* y = (float*)d_out;

  float* Sacc = (float*)d_ws;                                        // 480000 B
  unsigned short* AadT = (unsigned short*)((char*)d_ws + 512 * 1024); // 393216 B

  hipMemsetAsync(Sacc, 0, (size_t)K_ * N_ * V_ * V_ * sizeof(float), stream);
  k1_scores<<<dim3(75, 64), 256, 0, stream>>>(x, Wq, bq, Wk, bk, Sacc);
  k2_softmax<<<dim3(192), 64, 0, stream>>>(Sacc, A, AadT);
  k3_main<<<dim3(100, 64), 256, 0, stream>>>(x, W, b, AadT, y);
}

// Round 2
// 622.938 us; speedup vs baseline: 1.0104x; 1.0104x over previous
//
#include <hip/hip_runtime.h>

#define DI __device__ __forceinline__

typedef float f32x4 __attribute__((ext_vector_type(4)));
typedef short s16x8 __attribute__((ext_vector_type(8)));

constexpr int N_ = 64, T_ = 300, V_ = 25, C_ = 64, K_ = 3, F_ = 64, I_ = 16;

// round-to-nearest-even f32 -> bf16 (as raw short)
DI short f2bf(float f) {
  union { float f; unsigned u; } v; v.f = f;
  unsigned r = (v.u + 0x7fffu + ((v.u >> 16) & 1u)) >> 16;
  return (short)r;
}

// ---------------------------------------------------------------------------
// K1: grid (G, 64). Block (p, n): t-range [p*nChunks*4, (p+1)*nChunks*4).
//     Per 4-t chunk: P = x @ [Wq|Wk] + bias (MFMA), then S_k += q.k^T (MFMA,
//     accumulated in registers across chunks). End: plain stores of partials
//     to Spart[p][k*64+n][625]. NO atomics.
// ---------------------------------------------------------------------------
__global__ __launch_bounds__(256, 2) void k1_scores(
    const float* __restrict__ x,
    const float* __restrict__ Wq, const float* __restrict__ bq,
    const float* __restrict__ Wk, const float* __restrict__ bk,
    float* __restrict__ Spart, int nChunks)
{
  __shared__ __align__(16) short Xl[112 * 64];   // rows=(t,v) pad->112, cols=c (swz)
  __shared__ __align__(16) short Wt[96 * 64];    // rows=j(96), cols=c (swz)
  __shared__ __align__(16) short Pq[4 * 32 * 64];// [t][v(32)][j<48 pad 64] (swz by v)
  __shared__ __align__(16) short Pk[4 * 32 * 64];
  __shared__ float bcl[96];

  const int tid = threadIdx.x;
  const int lane = tid & 63;
  const int wid = tid >> 6;
  const int g = lane >> 4;
  const int lo = lane & 15;
  const int n = blockIdx.y;
  const int p = blockIdx.x;

  // stage combined q/k weights once, transposed+swizzled: Wt[j][c] = Wc[c][j]
  for (int idx = tid; idx < 96 * 64; idx += 256) {
    int j = idx >> 6, c = idx & 63;
    float v;
    if (j < 48) v = Wq[(j >> 4) * (C_ * I_) + c * I_ + (j & 15)];
    else { int j2 = j - 48; v = Wk[(j2 >> 4) * (C_ * I_) + c * I_ + (j2 & 15)]; }
    Wt[j * 64 + (c ^ ((j & 7) << 3))] = f2bf(v);
  }
  if (tid < 96) bcl[tid] = (tid < 48) ? bq[tid] : bk[tid - 48];

  // register accumulators: wave wid owns combos {wid, wid+4, wid+8}
  f32x4 acc[3];
#pragma unroll
  for (int j = 0; j < 3; ++j) acc[j] = (f32x4){0.f, 0.f, 0.f, 0.f};

  for (int chunk = 0; chunk < nChunks; ++chunk) {
    const int t0row = (p * nChunks + chunk) * 100;  // 4 t's * 25 v

    // stage x chunk (100 valid rows, pad rows zeroed). Writes Xl only — no
    // conflict with previous chunk's S-stage (reads Pq/Pk).
    {
      const float* xb = x + (size_t)n * (T_ * V_ * C_) + (size_t)t0row * C_;
      for (int idx = tid; idx < 112 * 64; idx += 256) {
        int row = idx >> 6, c = idx & 63;
        float v = (row < 100) ? xb[idx] : 0.f;
        Xl[row * 64 + (c ^ ((row & 7) << 3))] = f2bf(v);
      }
    }
    __syncthreads();

    // P-stage: 7 m-tiles x 6 n-tiles, K=64 (2 steps of 32)
    for (int i = 0; i < 11; ++i) {
      int tile = wid + i * 4;
      if (tile >= 42) break;
      int m = tile / 6, nt = tile % 6;
      float binit = bcl[nt * 16 + lo];
      f32x4 pacc = { binit, binit, binit, binit };
#pragma unroll
      for (int ks = 0; ks < 2; ++ks) {
        int arow = m * 16 + lo;
        s16x8 a = *(const s16x8*)&Xl[arow * 64 + ((ks * 32 + g * 8) ^ ((arow & 7) << 3))];
        int brow = nt * 16 + lo;
        s16x8 b = *(const s16x8*)&Wt[brow * 64 + ((ks * 32 + g * 8) ^ ((brow & 7) << 3))];
        pacc = __builtin_amdgcn_mfma_f32_16x16x32_bf16(a, b, pacc, 0, 0, 0);
      }
#pragma unroll
      for (int r = 0; r < 4; ++r) {
        int row = m * 16 + g * 4 + r;
        if (row < 100) {
          int t = row / 25, v = row - t * 25;
          int j = nt * 16 + lo;
          short val = f2bf(pacc[r]);
          if (j < 48) Pq[(t * 32 + v) * 64 + (j ^ ((v & 7) << 3))] = val;
          else        Pk[(t * 32 + v) * 64 + ((j - 48) ^ ((v & 7) << 3))] = val;
        }
      }
    }
    __syncthreads();

    // S-stage: combos (k, vt, wt), K-dim = (t,i) = 64 -> 2 steps of 32
#pragma unroll
    for (int j = 0; j < 3; ++j) {
      int combo = wid + j * 4;          // 0..11
      int k = combo >> 2, vt = (combo >> 1) & 1, wt = combo & 1;
#pragma unroll
      for (int ks = 0; ks < 2; ++ks) {
        int t = ks * 2 + (g >> 1);
        int ib = (g & 1) * 8;
        int v = vt * 16 + lo;
        s16x8 a = *(const s16x8*)&Pq[(t * 32 + v) * 64 + ((k * 16 + ib) ^ ((v & 7) << 3))];
        int w = wt * 16 + lo;
        s16x8 b = *(const s16x8*)&Pk[(t * 32 + w) * 64 + ((k * 16 + ib) ^ ((w & 7) << 3))];
        acc[j] = __builtin_amdgcn_mfma_f32_16x16x32_bf16(a, b, acc[j], 0, 0, 0);
      }
    }
  }

  // store partials (plain coalesced-ish stores, masked to 25x25)
#pragma unroll
  for (int j = 0; j < 3; ++j) {
    int combo = wid + j * 4;
    int k = combo >> 2, vt = (combo >> 1) & 1, wt = combo & 1;
#pragma unroll
    for (int r = 0; r < 4; ++r) {
      int v = vt * 16 + g * 4 + r;
      int w = wt * 16 + lo;
      if (v < 25 && w < 25)
        Spart[((size_t)p * 192 + (k * 64 + n)) * 625 + v * 25 + w] = acc[j][r];
    }
  }
}

// ---------------------------------------------------------------------------
// K2: reduce partials over p, softmax(S*scale) + A -> AadT (transposed [w][v],
//     bf16, zero-padded 32x32). 192 blocks x 256 threads.
// ---------------------------------------------------------------------------
__global__ void k2_softmax(const float* __restrict__ Spart,
                           const float* __restrict__ A,
                           unsigned short* __restrict__ AadT, int G)
{
  __shared__ float Ss[625];
  int bx = blockIdx.x;            // 0..191 = k*64 + n
  int k = bx >> 6;
  int tid = threadIdx.x;          // 256
  unsigned short* outb = AadT + (size_t)bx * 1024;
  for (int idx = tid; idx < 1024; idx += 256) outb[idx] = 0;

  for (int cell = tid; cell < 625; cell += 256) {
    float s = 0.f;
    for (int pp = 0; pp < G; ++pp)
      s += Spart[((size_t)pp * 192 + bx) * 625 + cell];
    Ss[cell] = s;
  }
  __syncthreads();

  if (tid < 25) {
    int v = tid;
    const float scale = 0.014433756729740645f;  // 1/sqrt(4800)
    float s[25];
    float mx = -1e30f;
#pragma unroll
    for (int w = 0; w < 25; ++w) { s[w] = Ss[v * 25 + w] * scale; mx = fmaxf(mx, s[w]); }
    float sum = 0.f;
#pragma unroll
    for (int w = 0; w < 25; ++w) { s[w] = __expf(s[w] - mx); sum += s[w]; }
    float inv = 1.f / sum;
#pragma unroll
    for (int w = 0; w < 25; ++w) {
      float aad = A[(k * 25 + v) * 25 + w] + s[w] * inv;
      outb[w * 32 + v] = (unsigned short)f2bf(aad);
    }
  }
}

// ---------------------------------------------------------------------------
// K3: per (n, chunk of 3 t's): h = x@W + b (MFMA, store transposed in LDS),
//     y[t][w][c] = sum_k sum_v AadT[k][w][v] * h[t][v][k*64+c] (MFMA), store y.
// ---------------------------------------------------------------------------
__global__ __launch_bounds__(256, 2) void k3_main(
    const float* __restrict__ x,
    const float* __restrict__ W, const float* __restrict__ b,
    const unsigned short* __restrict__ AadT, float* __restrict__ y)
{
  __shared__ __align__(16) short Xl[80 * 64];    // rows=(t,v) pad->80, cols=c (swz)
  __shared__ __align__(16) short Wt[192 * 64];   // rows=kc, cols=c (swz)
  __shared__ __align__(16) short Ht[192 * 96];   // rows=kc, cols=(t*32+v) (swz &3)
  __shared__ __align__(16) short Al[3 * 32 * 32];// [k][w][v] (swz &3)
  __shared__ float bl[192];

  const int tid = threadIdx.x;
  const int lane = tid & 63;
  const int wid = tid >> 6;
  const int g = lane >> 4;
  const int lo = lane & 15;
  const int n = blockIdx.y;
  const int t0 = blockIdx.x * 3;

  // stage W transposed+swizzled (coalesced global reads)
  for (int idx = tid; idx < 192 * 64; idx += 256) {
    int c = idx / 192, j = idx % 192;
    Wt[j * 64 + (c ^ ((j & 7) << 3))] = f2bf(W[idx]);
  }
  if (tid < 192) bl[tid] = b[tid];

  // stage AadT into LDS (swizzled); already zero-padded
  for (int idx = tid; idx < 3 * 1024; idx += 256) {
    int kk = idx >> 10, rem = idx & 1023, w = rem >> 5, v = rem & 31;
    unsigned short val = AadT[(size_t)(kk * 64 + n) * 1024 + rem];
    Al[(kk * 32 + w) * 32 + (v ^ ((w & 3) << 3))] = (short)val;
  }

  // zero Ht pad slots (v = 24..31) so 0*pad is clean in agg MFMA
  for (int idx = tid; idx < 192 * 24; idx += 256) {
    int kc = idx / 24, rem = idx % 24, t = rem >> 3, vv = 24 + (rem & 7);
    Ht[kc * 96 + ((t * 32 + vv) ^ ((kc & 3) << 3))] = 0;
  }

  // stage x chunk (75 valid rows)
  {
    const float* xb = x + (size_t)n * (T_ * V_ * C_) + (size_t)t0 * (V_ * C_);
    for (int idx = tid; idx < 80 * 64; idx += 256) {
      int row = idx >> 6, c = idx & 63;
      float v = (row < 75) ? xb[idx] : 0.f;
      Xl[row * 64 + (c ^ ((row & 7) << 3))] = f2bf(v);
    }
  }
  __syncthreads();

  // h-stage: 5 m-tiles x 12 n-tiles, K=64 (2 steps); store transposed into Ht
#pragma unroll
  for (int i = 0; i < 15; ++i) {
    int tile = wid + i * 4;            // 0..59
    int m = tile / 12, nt = tile % 12;
    float binit = bl[nt * 16 + lo];
    f32x4 acc = { binit, binit, binit, binit };
#pragma unroll
    for (int ks = 0; ks < 2; ++ks) {
      int arow = m * 16 + lo;
      s16x8 a = *(const s16x8*)&Xl[arow * 64 + ((ks * 32 + g * 8) ^ ((arow & 7) << 3))];
      int brow = nt * 16 + lo;
      s16x8 bb = *(const s16x8*)&Wt[brow * 64 + ((ks * 32 + g * 8) ^ ((brow & 7) << 3))];
      acc = __builtin_amdgcn_mfma_f32_16x16x32_bf16(a, bb, acc, 0, 0, 0);
    }
#pragma unroll
    for (int r = 0; r < 4; ++r) {
      int row = m * 16 + g * 4 + r;
      if (row < 75) {
        int t = row / 25, v = row - t * 25;
        int kc = nt * 16 + lo;
        Ht[kc * 96 + ((t * 32 + v) ^ ((kc & 3) << 3))] = f2bf(acc[r]);
      }
    }
  }
  __syncthreads();

  // agg: jobs (t, wt, ct); K-dim = v (32, one step); accumulate over k
#pragma unroll
  for (int i = 0; i < 6; ++i) {
    int job = wid + i * 4;             // 0..23
    int t = job >> 3, rem = job & 7, wt = rem >> 2, ct = rem & 3;
    f32x4 acc = { 0.f, 0.f, 0.f, 0.f };
#pragma unroll
    for (int k3 = 0; k3 < 3; ++k3) {
      int w = wt * 16 + lo;
      s16x8 a = *(const s16x8*)&Al[(k3 * 32 + w) * 32 + ((g * 8) ^ ((w & 3) << 3))];
      int kc = k3 * 64 + ct * 16 + lo;
      s16x8 bb = *(const s16x8*)&Ht[kc * 96 + ((t * 32 + g * 8) ^ ((kc & 3) << 3))];
      acc = __builtin_amdgcn_mfma_f32_16x16x32_bf16(a, bb, acc, 0, 0, 0);
    }
#pragma unroll
    for (int r = 0; r < 4; ++r) {
      int w = wt * 16 + g * 4 + r;
      if (w < 25)
        y[(((size_t)n * T_ + t0 + t) * V_ + w) * C_ + ct * 16 + lo] = acc[r];
    }
  }
}

extern "C" void kernel_launch(void* const* d_in, const int* in_sizes, int n_in,
                              void* d_out, int out_size, void* d_ws, size_t ws_size,
                              hipStream_t stream) {
  const float* x  = (const float*)d_in[0];
  const float* A  = (const float*)d_in[1];
  const float* W  = (const float*)d_in[2];
  const float* b  = (const float*)d_in[3];
  const float* Wq = (const float*)d_in[4];
  const float* bq = (const float*)d_in[5];
  const float* Wk = (const float*)d_in[6];
  const float* bk = (const float*)d_in[7];
  float* y = (float*)d_out;

  unsigned short* AadT = (unsigned short*)d_ws;            // 393216 B
  float* Spart = (float*)((char*)d_ws + 512 * 1024);       // G*192*625*4 B

  // pick largest G whose partial buffer fits the workspace
  const size_t base = 512 * 1024;
  const size_t perG = (size_t)192 * 625 * sizeof(float);   // 480000 B
  int G = 25;
  if (base + 25 * perG > ws_size) G = 15;
  if (base + 15 * perG > ws_size) G = 5;
  int nChunks = 75 / G;  // 4-t chunks per block

  k1_scores<<<dim3(G, 64), 256, 0, stream>>>(x, Wq, bq, Wk, bk, Spart, nChunks);
  k2_softmax<<<dim3(192), 256, 0, stream>>>(Spart, A, AadT, G);
  k3_main<<<dim3(100, 64), 256, 0, stream>>>(x, W, b, AadT, y);
}